// Round 4
// baseline (570.104 us; speedup 1.0000x reference)
//
#include <hip/hip_runtime.h>
#include <hip/hip_bf16.h>
#include <stdint.h>

typedef unsigned short u16;
typedef __bf16 bf16x8 __attribute__((ext_vector_type(8)));
typedef float f32x4 __attribute__((ext_vector_type(4)));

__device__ __forceinline__ u16 f2bf(float f) {
  union { float f; uint32_t u; } v; v.f = f;
  uint32_t u = v.u;
  return (u16)((u + 0x7FFFu + ((u >> 16) & 1u)) >> 16);
}

__device__ __forceinline__ f32x4 mfma16(bf16x8 a, bf16x8 b, f32x4 c) {
  return __builtin_amdgcn_mfma_f32_16x16x32_bf16(a, b, c, 0, 0, 0);
}

#define GLOBAL_TO_LDS16(g, l)                                                  \
  __builtin_amdgcn_global_load_lds(                                            \
      (const __attribute__((address_space(1))) void*)(g),                      \
      (__attribute__((address_space(3))) void*)(l), 16, 0, 0)

// ---------------- f32 -> bf16 conversion ----------------
__global__ void cvt_bf16(const float* __restrict__ src, u16* __restrict__ dst, int n4) {
  int i = blockIdx.x * 256 + threadIdx.x;
  if (i < n4) {
    float4 f = ((const float4*)src)[i];
    ushort4 o;
    o.x = f2bf(f.x); o.y = f2bf(f.y); o.z = f2bf(f.z); o.w = f2bf(f.w);
    ((ushort4*)dst)[i] = o;
  }
}

// ---------------- QKV GEMM ----------------
// SWAP=1 (q/k blocks): mfma(b,a) -> regs hold 4 consecutive n(=d) -> ushort4
// stores into q/k [bh][seq][64]. SWAP=0 (v blocks): regs hold 4 consecutive
// m(=seq) -> ushort4 stores into vT [bh][d][128].
template <bool SWAP>
__global__ __launch_bounds__(256) void qkv_gemm(
    const u16* __restrict__ A, const u16* __restrict__ Bt, int nbase,
    u16* __restrict__ q, u16* __restrict__ k, u16* __restrict__ vT) {
  const int K = 768;
  __shared__ u16 As[128 * 64];
  __shared__ u16 Bs[128 * 64];
  int tid = threadIdx.x;
  int wave = tid >> 6, lane = tid & 63;
  int quad = lane >> 4, lrow = lane & 15;
  int m0 = blockIdx.y * 128, n0 = nbase + blockIdx.x * 128;
  int wr = (wave >> 1) * 64, wc = (wave & 1) * 64;

  const u16* asrc[4]; const u16* bsrc[4]; int ldst[4];
#pragma unroll
  for (int s = 0; s < 4; s++) {
    int p = (wave * 4 + s) * 64 + lane;
    int row = p >> 3, cp = p & 7;
    int c = cp ^ (row & 7);
    asrc[s] = A + (size_t)(m0 + row) * K + c * 8;
    bsrc[s] = Bt + (size_t)(n0 + row) * K + c * 8;
    ldst[s] = p * 8;
  }
  f32x4 acc[4][4] = {};
  for (int k0 = 0; k0 < K; k0 += 64) {
#pragma unroll
    for (int s = 0; s < 4; s++) {
      GLOBAL_TO_LDS16(asrc[s] + k0, As + ldst[s]);
      GLOBAL_TO_LDS16(bsrc[s] + k0, Bs + ldst[s]);
    }
    __syncthreads();
#pragma unroll
    for (int kk = 0; kk < 2; kk++) {
      bf16x8 am[4], bn[4];
#pragma unroll
      for (int i = 0; i < 4; i++) {
        int r = wr + i * 16 + lrow;
        am[i] = *(const bf16x8*)(As + r * 64 + ((((kk << 2) | quad) ^ (r & 7)) << 3));
      }
#pragma unroll
      for (int j = 0; j < 4; j++) {
        int r = wc + j * 16 + lrow;
        bn[j] = *(const bf16x8*)(Bs + r * 64 + ((((kk << 2) | quad) ^ (r & 7)) << 3));
      }
#pragma unroll
      for (int i = 0; i < 4; i++)
#pragma unroll
        for (int j = 0; j < 4; j++)
          acc[i][j] = SWAP ? mfma16(bn[i], am[j], acc[i][j])
                           : mfma16(am[i], bn[j], acc[i][j]);
    }
    __syncthreads();
  }
  int b = m0 >> 7;  // block spans exactly one batch row
  if (SWAP) {
    // i -> n tiles (regs: 4 consecutive n), j -> m tiles (lane: lrow)
    int t = n0 / 768;
    float s = (t == 0) ? 0.125f : 1.0f;
    u16* dst = (t == 0) ? q : k;
#pragma unroll
    for (int i = 0; i < 4; i++) {
      int nb = (n0 - t * 768) + wc + i * 16 + quad * 4;
      int h = nb >> 6, d0 = nb & 63;
#pragma unroll
      for (int j = 0; j < 4; j++) {
        int seq = wr + j * 16 + lrow;
        ushort4 o;
        o.x = f2bf(acc[i][j][0] * s); o.y = f2bf(acc[i][j][1] * s);
        o.z = f2bf(acc[i][j][2] * s); o.w = f2bf(acc[i][j][3] * s);
        *(ushort4*)(dst + ((size_t)(b * 12 + h)) * 8192 + seq * 64 + d0) = o;
      }
    }
  } else {
    // i -> m tiles (regs: 4 consecutive seq), j -> n tiles (lane: lrow)
#pragma unroll
    for (int j = 0; j < 4; j++) {
      int nb = (n0 - 1536) + wc + j * 16 + lrow;
      int h = nb >> 6, d = nb & 63;
#pragma unroll
      for (int i = 0; i < 4; i++) {
        int seq0 = wr + i * 16 + quad * 4;
        ushort4 o;
        o.x = f2bf(acc[i][j][0]); o.y = f2bf(acc[i][j][1]);
        o.z = f2bf(acc[i][j][2]); o.w = f2bf(acc[i][j][3]);
        *(ushort4*)(vT + ((size_t)(b * 12 + h)) * 8192 + d * 128 + seq0) = o;
      }
    }
  }
}

// ---------------- attention: one block per (b,h) ----------------
__global__ __launch_bounds__(256) void attn_kernel(
    const u16* __restrict__ q, const u16* __restrict__ k, const u16* __restrict__ vT,
    const float* __restrict__ mask, const float* __restrict__ bias_table,
    u16* __restrict__ attn_out) {
  // phase 1: qs[128*64] | ks[128*64]  (XOR chunk swizzle)
  // phase 2: same region re-used as P[128][128], stride 128, XOR swizzle
  __shared__ u16 smem[2 * 128 * 64];
  __shared__ u16 vTs[64 * 128];
  __shared__ float bias_s[255];
  u16* qs = smem;
  u16* ks = smem + 128 * 64;
  u16* ps = smem;
  int tid = threadIdx.x;
  int wave = tid >> 6, lane = tid & 63;
  int quad = lane >> 4, lrow = lane & 15;
  int bh = blockIdx.x;
  int b = bh / 12, h = bh - b * 12;
  int w = b & 63;
  if (tid < 255) bias_s[tid] = bias_table[tid * 12 + h];
  const u16* qg = q + (size_t)bh * 8192;
  const u16* kg = k + (size_t)bh * 8192;
  const u16* vg = vT + (size_t)bh * 8192;
#pragma unroll
  for (int s = 0; s < 4; s++) {
    int p = wave * 256 + s * 64 + lane;
    int row = p >> 3, c = (p & 7) ^ (row & 7);
    GLOBAL_TO_LDS16(qg + row * 64 + c * 8, qs + p * 8);
    GLOBAL_TO_LDS16(kg + row * 64 + c * 8, ks + p * 8);
    int dd = p >> 4, cv = (p & 15) ^ (dd & 7);
    GLOBAL_TO_LDS16(vg + dd * 128 + cv * 8, vTs + p * 8);
  }
  __syncthreads();

  // S = q k^T : rows [wave*32, wave*32+32)
  f32x4 sacc[2][8] = {};
#pragma unroll
  for (int kk = 0; kk < 2; kk++) {
    bf16x8 av[2], bv[8];
#pragma unroll
    for (int i = 0; i < 2; i++) {
      int r = wave * 32 + i * 16 + lrow;
      av[i] = *(const bf16x8*)(qs + r * 64 + ((((kk << 2) | quad) ^ (r & 7)) << 3));
    }
#pragma unroll
    for (int j = 0; j < 8; j++) {
      int r = j * 16 + lrow;
      bv[j] = *(const bf16x8*)(ks + r * 64 + ((((kk << 2) | quad) ^ (r & 7)) << 3));
    }
#pragma unroll
    for (int i = 0; i < 2; i++)
#pragma unroll
      for (int j = 0; j < 8; j++)
        sacc[i][j] = mfma16(av[i], bv[j], sacc[i][j]);
  }
  const float* mrow = mask + (size_t)w * 16384;
#pragma unroll
  for (int i = 0; i < 2; i++)
#pragma unroll
    for (int j = 0; j < 8; j++)
#pragma unroll
      for (int r = 0; r < 4; r++) {
        int row = wave * 32 + i * 16 + quad * 4 + r;
        int col = j * 16 + lrow;
        sacc[i][j][r] += bias_s[row - col + 127] + mrow[row * 128 + col];
      }
  // in-register softmax (row lives across lrow lanes x 8 regs)
#pragma unroll
  for (int i = 0; i < 2; i++)
#pragma unroll
    for (int r = 0; r < 4; r++) {
      float m = sacc[i][0][r];
#pragma unroll
      for (int j = 1; j < 8; j++) m = fmaxf(m, sacc[i][j][r]);
#pragma unroll
      for (int d = 1; d < 16; d <<= 1) m = fmaxf(m, __shfl_xor(m, d, 64));
      float sum = 0.f;
#pragma unroll
      for (int j = 0; j < 8; j++) {
        float e = __expf(sacc[i][j][r] - m);
        sacc[i][j][r] = e;
        sum += e;
      }
#pragma unroll
      for (int d = 1; d < 16; d <<= 1) sum += __shfl_xor(sum, d, 64);
      float inv = 1.f / sum;
#pragma unroll
      for (int j = 0; j < 8; j++) sacc[i][j][r] *= inv;
    }
  __syncthreads();   // qs/ks reads complete -> ps may alias them
  // P[128][128] store, stride 128, chunk position = chunk ^ (row&7)
#pragma unroll
  for (int i = 0; i < 2; i++)
#pragma unroll
    for (int j = 0; j < 8; j++)
#pragma unroll
      for (int r = 0; r < 4; r++) {
        int row = wave * 32 + i * 16 + quad * 4 + r;
        int col = j * 16 + lrow;
        int pos = (col >> 3) ^ (row & 7);
        ps[row * 128 + pos * 8 + (col & 7)] = f2bf(sacc[i][j][r]);
      }
  __syncthreads();

  // O^T = V^T P^T via mfma(vfrag, pfrag): regs hold 4 consecutive d
  f32x4 oacc[4][2] = {};
#pragma unroll
  for (int kk = 0; kk < 4; kk++) {
    bf16x8 vf[4], pf[2];
#pragma unroll
    for (int jd = 0; jd < 4; jd++) {
      int r = jd * 16 + lrow;
      vf[jd] = *(const bf16x8*)(vTs + r * 128 + ((((kk << 2) | quad) ^ (r & 7)) << 3));
    }
#pragma unroll
    for (int i = 0; i < 2; i++) {
      int r = wave * 32 + i * 16 + lrow;
      pf[i] = *(const bf16x8*)(ps + r * 128 + ((((kk << 2) | quad) ^ (r & 7)) << 3));
    }
#pragma unroll
    for (int jd = 0; jd < 4; jd++)
#pragma unroll
      for (int i = 0; i < 2; i++)
        oacc[jd][i] = mfma16(vf[jd], pf[i], oacc[jd][i]);
  }
#pragma unroll
  for (int jd = 0; jd < 4; jd++) {
    int d0 = jd * 16 + quad * 4;
#pragma unroll
    for (int i = 0; i < 2; i++) {
      int seq = wave * 32 + i * 16 + lrow;
      ushort4 o;
      o.x = f2bf(oacc[jd][i][0]); o.y = f2bf(oacc[jd][i][1]);
      o.z = f2bf(oacc[jd][i][2]); o.w = f2bf(oacc[jd][i][3]);
      *(ushort4*)(attn_out + ((size_t)(b * 128 + seq)) * 768 + h * 64 + d0) = o;
    }
  }
}

// ---------------- proj GEMM (swapped orientation, float4 stores) ----------
__global__ __launch_bounds__(256) void proj_gemm(
    const u16* __restrict__ A, const u16* __restrict__ Bt,
    const float* __restrict__ bias, float* __restrict__ out) {
  const int K = 768;
  __shared__ u16 As[128 * 64];
  __shared__ u16 Bs[128 * 64];
  int tid = threadIdx.x;
  int wave = tid >> 6, lane = tid & 63;
  int quad = lane >> 4, lrow = lane & 15;
  int m0 = blockIdx.y * 128, n0 = blockIdx.x * 128;
  int wr = (wave >> 1) * 64, wc = (wave & 1) * 64;

  const u16* asrc[4]; const u16* bsrc[4]; int ldst[4];
#pragma unroll
  for (int s = 0; s < 4; s++) {
    int p = (wave * 4 + s) * 64 + lane;
    int row = p >> 3, c = (p & 7) ^ (row & 7);
    asrc[s] = A + (size_t)(m0 + row) * K + c * 8;
    bsrc[s] = Bt + (size_t)(n0 + row) * K + c * 8;
    ldst[s] = p * 8;
  }
  f32x4 acc[4][4] = {};
  for (int k0 = 0; k0 < K; k0 += 64) {
#pragma unroll
    for (int s = 0; s < 4; s++) {
      GLOBAL_TO_LDS16(asrc[s] + k0, As + ldst[s]);
      GLOBAL_TO_LDS16(bsrc[s] + k0, Bs + ldst[s]);
    }
    __syncthreads();
#pragma unroll
    for (int kk = 0; kk < 2; kk++) {
      bf16x8 am[4], bn[4];
#pragma unroll
      for (int i = 0; i < 4; i++) {
        int r = wr + i * 16 + lrow;
        am[i] = *(const bf16x8*)(As + r * 64 + ((((kk << 2) | quad) ^ (r & 7)) << 3));
      }
#pragma unroll
      for (int j = 0; j < 4; j++) {
        int r = wc + j * 16 + lrow;
        bn[j] = *(const bf16x8*)(Bs + r * 64 + ((((kk << 2) | quad) ^ (r & 7)) << 3));
      }
#pragma unroll
      for (int i = 0; i < 4; i++)
#pragma unroll
        for (int j = 0; j < 4; j++)
          acc[i][j] = mfma16(bn[i], am[j], acc[i][j]);  // swapped: regs = 4 consecutive n
    }
    __syncthreads();
  }
#pragma unroll
  for (int i = 0; i < 4; i++) {
    int nb = n0 + wc + i * 16 + quad * 4;
    float4 b4 = *(const float4*)(bias + nb);
#pragma unroll
    for (int j = 0; j < 4; j++) {
      int m = m0 + wr + j * 16 + lrow;
      float4 o;
      o.x = acc[i][j][0] + b4.x; o.y = acc[i][j][1] + b4.y;
      o.z = acc[i][j][2] + b4.z; o.w = acc[i][j][3] + b4.w;
      *(float4*)(out + (size_t)m * 768 + nb) = o;
    }
  }
}

extern "C" void kernel_launch(void* const* d_in, const int* in_sizes, int n_in,
                              void* d_out, int out_size, void* d_ws, size_t ws_size,
                              hipStream_t stream) {
  const float* x          = (const float*)d_in[0];
  const float* mask       = (const float*)d_in[1];
  const float* qkv_w      = (const float*)d_in[2];
  const float* bias_table = (const float*)d_in[3];
  const float* proj_w     = (const float*)d_in[4];
  const float* proj_b     = (const float*)d_in[5];
  float* out = (float*)d_out;
  char* ws = (char*)d_ws;
  u16* q_b    = (u16*)(ws);                    // 50331648
  u16* k_b    = (u16*)(ws + 50331648);         // 50331648
  u16* vT_b   = (u16*)(ws + 100663296);        // 50331648
  u16* x_b    = (u16*)(ws + 150994944);        // 50331648 (x bf16, reused as attn_out)
  u16* qw_b   = (u16*)(ws + 201326592);        // 3538944
  u16* pw_b   = (u16*)(ws + 204865536);        // 1179648
  u16* attn_b = x_b;

  cvt_bf16<<<24576, 256, 0, stream>>>(x, x_b, 6291456);
  cvt_bf16<<<1728, 256, 0, stream>>>(qkv_w, qw_b, 442368);
  cvt_bf16<<<576, 256, 0, stream>>>(proj_w, pw_b, 147456);
  qkv_gemm<true><<<dim3(12, 256), 256, 0, stream>>>(x_b, qw_b, 0, q_b, k_b, vT_b);
  qkv_gemm<false><<<dim3(6, 256), 256, 0, stream>>>(x_b, qw_b, 1536, q_b, k_b, vT_b);
  attn_kernel<<<3072, 256, 0, stream>>>(q_b, k_b, vT_b, mask, bias_table, attn_b);
  proj_gemm<<<dim3(6, 256), 256, 0, stream>>>(attn_b, pw_b, proj_b, out);
}

// Round 5
// 482.674 us; speedup vs baseline: 1.1811x; 1.1811x over previous
//
#include <hip/hip_runtime.h>
#include <hip/hip_bf16.h>
#include <stdint.h>

typedef unsigned short u16;
typedef __bf16 bf16x8 __attribute__((ext_vector_type(8)));
typedef float f32x4 __attribute__((ext_vector_type(4)));

__device__ __forceinline__ u16 f2bf(float f) {
  union { float f; uint32_t u; } v; v.f = f;
  uint32_t u = v.u;
  return (u16)((u + 0x7FFFu + ((u >> 16) & 1u)) >> 16);
}

__device__ __forceinline__ f32x4 mfma16(bf16x8 a, bf16x8 b, f32x4 c) {
  return __builtin_amdgcn_mfma_f32_16x16x32_bf16(a, b, c, 0, 0, 0);
}

#define GLOBAL_TO_LDS16(g, l)                                                  \
  __builtin_amdgcn_global_load_lds(                                            \
      (const __attribute__((address_space(1))) void*)(g),                      \
      (__attribute__((address_space(3))) void*)(l), 16, 0, 0)

// ---------------- fused f32 -> bf16 conversion (x | qkv_w | proj_w) --------
__global__ void cvt_bf16_all(const float* __restrict__ x, u16* __restrict__ xb,
                             const float* __restrict__ qw, u16* __restrict__ qwb,
                             const float* __restrict__ pw, u16* __restrict__ pwb) {
  int blk = blockIdx.x;
  const float* src; u16* dst; int i;
  if (blk < 24576)        { src = x;  dst = xb;  i = blk * 256 + threadIdx.x; }
  else if (blk < 26304)   { src = qw; dst = qwb; i = (blk - 24576) * 256 + threadIdx.x; }
  else                    { src = pw; dst = pwb; i = (blk - 26304) * 256 + threadIdx.x; }
  float4 f = ((const float4*)src)[i];
  ushort4 o;
  o.x = f2bf(f.x); o.y = f2bf(f.y); o.z = f2bf(f.z); o.w = f2bf(f.w);
  ((ushort4*)dst)[i] = o;
}

// ---------------- QKV GEMM (unchanged from R3-verified) ----------------
template <bool SWAP>
__global__ __launch_bounds__(256) void qkv_gemm(
    const u16* __restrict__ A, const u16* __restrict__ Bt, int nbase,
    u16* __restrict__ q, u16* __restrict__ k, u16* __restrict__ vT) {
  const int K = 768;
  __shared__ u16 As[128 * 64];
  __shared__ u16 Bs[128 * 64];
  int tid = threadIdx.x;
  int wave = tid >> 6, lane = tid & 63;
  int quad = lane >> 4, lrow = lane & 15;
  int m0 = blockIdx.y * 128, n0 = nbase + blockIdx.x * 128;
  int wr = (wave >> 1) * 64, wc = (wave & 1) * 64;

  const u16* asrc[4]; const u16* bsrc[4]; int ldst[4];
#pragma unroll
  for (int s = 0; s < 4; s++) {
    int p = (wave * 4 + s) * 64 + lane;
    int row = p >> 3, cp = p & 7;
    int c = cp ^ (row & 7);
    asrc[s] = A + (size_t)(m0 + row) * K + c * 8;
    bsrc[s] = Bt + (size_t)(n0 + row) * K + c * 8;
    ldst[s] = p * 8;
  }
  f32x4 acc[4][4] = {};
  for (int k0 = 0; k0 < K; k0 += 64) {
#pragma unroll
    for (int s = 0; s < 4; s++) {
      GLOBAL_TO_LDS16(asrc[s] + k0, As + ldst[s]);
      GLOBAL_TO_LDS16(bsrc[s] + k0, Bs + ldst[s]);
    }
    __syncthreads();
#pragma unroll
    for (int kk = 0; kk < 2; kk++) {
      bf16x8 am[4], bn[4];
#pragma unroll
      for (int i = 0; i < 4; i++) {
        int r = wr + i * 16 + lrow;
        am[i] = *(const bf16x8*)(As + r * 64 + ((((kk << 2) | quad) ^ (r & 7)) << 3));
      }
#pragma unroll
      for (int j = 0; j < 4; j++) {
        int r = wc + j * 16 + lrow;
        bn[j] = *(const bf16x8*)(Bs + r * 64 + ((((kk << 2) | quad) ^ (r & 7)) << 3));
      }
#pragma unroll
      for (int i = 0; i < 4; i++)
#pragma unroll
        for (int j = 0; j < 4; j++)
          acc[i][j] = SWAP ? mfma16(bn[i], am[j], acc[i][j])
                           : mfma16(am[i], bn[j], acc[i][j]);
    }
    __syncthreads();
  }
  int b = m0 >> 7;
  if (SWAP) {
    int t = n0 / 768;
    float s = (t == 0) ? 0.125f : 1.0f;
    u16* dst = (t == 0) ? q : k;
#pragma unroll
    for (int i = 0; i < 4; i++) {
      int nb = (n0 - t * 768) + wc + i * 16 + quad * 4;
      int h = nb >> 6, d0 = nb & 63;
#pragma unroll
      for (int j = 0; j < 4; j++) {
        int seq = wr + j * 16 + lrow;
        ushort4 o;
        o.x = f2bf(acc[i][j][0] * s); o.y = f2bf(acc[i][j][1] * s);
        o.z = f2bf(acc[i][j][2] * s); o.w = f2bf(acc[i][j][3] * s);
        *(ushort4*)(dst + ((size_t)(b * 12 + h)) * 8192 + seq * 64 + d0) = o;
      }
    }
  } else {
#pragma unroll
    for (int j = 0; j < 4; j++) {
      int nb = (n0 - 1536) + wc + j * 16 + lrow;
      int h = nb >> 6, d = nb & 63;
#pragma unroll
      for (int i = 0; i < 4; i++) {
        int seq0 = wr + i * 16 + quad * 4;
        ushort4 o;
        o.x = f2bf(acc[i][j][0]); o.y = f2bf(acc[i][j][1]);
        o.z = f2bf(acc[i][j][2]); o.w = f2bf(acc[i][j][3]);
        *(ushort4*)(vT + ((size_t)(b * 12 + h)) * 8192 + d * 128 + seq0) = o;
      }
    }
  }
}

// ---------------- attention: one block per (b,h), 512 threads -------------
// S computed TRANSPOSED: mfma(k_frag, q_frag) -> lane holds S^T tile:
//   col(key) = i*16 + quad*4 + r (4 consecutive keys per reg),
//   row(query) = wave*16 + lrow.
// => mask add via float4, softmax reduce = 32-reg in-lane + shfl_xor(16,32),
//    P written to LDS as packed 8B ds_write (row-major, XOR chunk swizzle).
__global__ __launch_bounds__(512) void attn_kernel(
    const u16* __restrict__ q, const u16* __restrict__ k, const u16* __restrict__ vT,
    const float* __restrict__ mask, const float* __restrict__ bias_table,
    u16* __restrict__ attn_out) {
  __shared__ u16 smem[2 * 128 * 64];  // qs | ks, then P[128][128]
  __shared__ u16 vTs[64 * 128];
  __shared__ float bias_s[255];
  u16* qs = smem;
  u16* ks = smem + 128 * 64;
  u16* ps = smem;
  int tid = threadIdx.x;
  int wave = tid >> 6, lane = tid & 63;
  int quad = lane >> 4, lrow = lane & 15;
  int bh = blockIdx.x;
  int b = bh / 12, h = bh - b * 12;
  int w = b & 63;
  if (tid < 255) bias_s[tid] = bias_table[tid * 12 + h];
  const u16* qg = q + (size_t)bh * 8192;
  const u16* kg = k + (size_t)bh * 8192;
  const u16* vg = vT + (size_t)bh * 8192;
#pragma unroll
  for (int s = 0; s < 2; s++) {
    int p = s * 512 + tid;
    int row = p >> 3, c = (p & 7) ^ (row & 7);
    GLOBAL_TO_LDS16(qg + row * 64 + c * 8, qs + p * 8);
    GLOBAL_TO_LDS16(kg + row * 64 + c * 8, ks + p * 8);
    int dd = p >> 4, cv = (p & 15) ^ (dd & 7);
    GLOBAL_TO_LDS16(vg + dd * 128 + cv * 8, vTs + p * 8);
  }
  __syncthreads();

  int row = wave * 16 + lrow;  // this lane's query row
  // S^T: sacc[i] covers keys [i*16, i*16+16), rows of this wave
  f32x4 sacc[8] = {};
#pragma unroll
  for (int kk = 0; kk < 2; kk++) {
    bf16x8 qf = *(const bf16x8*)(qs + row * 64 + ((((kk << 2) | quad) ^ (row & 7)) << 3));
#pragma unroll
    for (int i = 0; i < 8; i++) {
      int rk = i * 16 + lrow;
      bf16x8 kf = *(const bf16x8*)(ks + rk * 64 + ((((kk << 2) | quad) ^ (rk & 7)) << 3));
      sacc[i] = mfma16(kf, qf, sacc[i]);
    }
  }
  // bias + mask (float4: 4 consecutive key-cols per reg)
  const float* mrow = mask + (size_t)w * 16384 + row * 128;
#pragma unroll
  for (int i = 0; i < 8; i++) {
    int c0 = i * 16 + quad * 4;
    float4 m4 = *(const float4*)(mrow + c0);
    sacc[i][0] += bias_s[row - (c0 + 0) + 127] + m4.x;
    sacc[i][1] += bias_s[row - (c0 + 1) + 127] + m4.y;
    sacc[i][2] += bias_s[row - (c0 + 2) + 127] + m4.z;
    sacc[i][3] += bias_s[row - (c0 + 3) + 127] + m4.w;
  }
  // softmax over the row: 32 in-lane values + quad lanes (xor 16, 32)
  float mx = sacc[0][0];
#pragma unroll
  for (int i = 0; i < 8; i++)
#pragma unroll
    for (int r = 0; r < 4; r++) mx = fmaxf(mx, sacc[i][r]);
  mx = fmaxf(mx, __shfl_xor(mx, 16, 64));
  mx = fmaxf(mx, __shfl_xor(mx, 32, 64));
  float sum = 0.f;
#pragma unroll
  for (int i = 0; i < 8; i++)
#pragma unroll
    for (int r = 0; r < 4; r++) {
      float e = __expf(sacc[i][r] - mx);
      sacc[i][r] = e;
      sum += e;
    }
  sum += __shfl_xor(sum, 16, 64);
  sum += __shfl_xor(sum, 32, 64);
  float inv = 1.f / sum;
  __syncthreads();  // qs/ks reads done -> safe to overwrite with P
  // P[128][128] row-major, chunk(8 elts) at position chunk^(row&7); packed 8B
#pragma unroll
  for (int i = 0; i < 8; i++) {
    int chunk = i * 2 + (quad >> 1);
    int pos = chunk ^ (row & 7);
    ushort4 o;
    o.x = f2bf(sacc[i][0] * inv); o.y = f2bf(sacc[i][1] * inv);
    o.z = f2bf(sacc[i][2] * inv); o.w = f2bf(sacc[i][3] * inv);
    *(ushort4*)(ps + row * 128 + pos * 8 + (quad & 1) * 4) = o;
  }
  __syncthreads();

  // O^T = mfma(v_frag, p_frag): regs hold 4 consecutive d
  f32x4 oacc[4] = {};
#pragma unroll
  for (int kk = 0; kk < 4; kk++) {
    bf16x8 pf = *(const bf16x8*)(ps + row * 128 + ((((kk << 2) | quad) ^ (row & 7)) << 3));
#pragma unroll
    for (int jd = 0; jd < 4; jd++) {
      int rd = jd * 16 + lrow;
      bf16x8 vf = *(const bf16x8*)(vTs + rd * 128 + ((((kk << 2) | quad) ^ (rd & 7)) << 3));
      oacc[jd] = mfma16(vf, pf, oacc[jd]);
    }
  }
#pragma unroll
  for (int jd = 0; jd < 4; jd++) {
    int d0 = jd * 16 + quad * 4;
    int seq = wave * 16 + lrow;
    ushort4 o;
    o.x = f2bf(oacc[jd][0]); o.y = f2bf(oacc[jd][1]);
    o.z = f2bf(oacc[jd][2]); o.w = f2bf(oacc[jd][3]);
    *(ushort4*)(attn_out + ((size_t)(b * 128 + seq)) * 768 + h * 64 + d0) = o;
  }
}

// ---------------- proj GEMM (unchanged from R3-verified) ----------------
__global__ __launch_bounds__(256) void proj_gemm(
    const u16* __restrict__ A, const u16* __restrict__ Bt,
    const float* __restrict__ bias, float* __restrict__ out) {
  const int K = 768;
  __shared__ u16 As[128 * 64];
  __shared__ u16 Bs[128 * 64];
  int tid = threadIdx.x;
  int wave = tid >> 6, lane = tid & 63;
  int quad = lane >> 4, lrow = lane & 15;
  int m0 = blockIdx.y * 128, n0 = blockIdx.x * 128;
  int wr = (wave >> 1) * 64, wc = (wave & 1) * 64;

  const u16* asrc[4]; const u16* bsrc[4]; int ldst[4];
#pragma unroll
  for (int s = 0; s < 4; s++) {
    int p = (wave * 4 + s) * 64 + lane;
    int row = p >> 3, c = (p & 7) ^ (row & 7);
    asrc[s] = A + (size_t)(m0 + row) * K + c * 8;
    bsrc[s] = Bt + (size_t)(n0 + row) * K + c * 8;
    ldst[s] = p * 8;
  }
  f32x4 acc[4][4] = {};
  for (int k0 = 0; k0 < K; k0 += 64) {
#pragma unroll
    for (int s = 0; s < 4; s++) {
      GLOBAL_TO_LDS16(asrc[s] + k0, As + ldst[s]);
      GLOBAL_TO_LDS16(bsrc[s] + k0, Bs + ldst[s]);
    }
    __syncthreads();
#pragma unroll
    for (int kk = 0; kk < 2; kk++) {
      bf16x8 am[4], bn[4];
#pragma unroll
      for (int i = 0; i < 4; i++) {
        int r = wr + i * 16 + lrow;
        am[i] = *(const bf16x8*)(As + r * 64 + ((((kk << 2) | quad) ^ (r & 7)) << 3));
      }
#pragma unroll
      for (int j = 0; j < 4; j++) {
        int r = wc + j * 16 + lrow;
        bn[j] = *(const bf16x8*)(Bs + r * 64 + ((((kk << 2) | quad) ^ (r & 7)) << 3));
      }
#pragma unroll
      for (int i = 0; i < 4; i++)
#pragma unroll
        for (int j = 0; j < 4; j++)
          acc[i][j] = mfma16(bn[i], am[j], acc[i][j]);
    }
    __syncthreads();
  }
#pragma unroll
  for (int i = 0; i < 4; i++) {
    int nb = n0 + wc + i * 16 + quad * 4;
    float4 b4 = *(const float4*)(bias + nb);
#pragma unroll
    for (int j = 0; j < 4; j++) {
      int m = m0 + wr + j * 16 + lrow;
      float4 o;
      o.x = acc[i][j][0] + b4.x; o.y = acc[i][j][1] + b4.y;
      o.z = acc[i][j][2] + b4.z; o.w = acc[i][j][3] + b4.w;
      *(float4*)(out + (size_t)m * 768 + nb) = o;
    }
  }
}

extern "C" void kernel_launch(void* const* d_in, const int* in_sizes, int n_in,
                              void* d_out, int out_size, void* d_ws, size_t ws_size,
                              hipStream_t stream) {
  const float* x          = (const float*)d_in[0];
  const float* mask       = (const float*)d_in[1];
  const float* qkv_w      = (const float*)d_in[2];
  const float* bias_table = (const float*)d_in[3];
  const float* proj_w     = (const float*)d_in[4];
  const float* proj_b     = (const float*)d_in[5];
  float* out = (float*)d_out;
  char* ws = (char*)d_ws;
  u16* q_b    = (u16*)(ws);                    // 50331648
  u16* k_b    = (u16*)(ws + 50331648);         // 50331648
  u16* vT_b   = (u16*)(ws + 100663296);        // 50331648
  u16* x_b    = (u16*)(ws + 150994944);        // 50331648 (x bf16, reused as attn_out)
  u16* qw_b   = (u16*)(ws + 201326592);        // 3538944
  u16* pw_b   = (u16*)(ws + 204865536);        // 1179648
  u16* attn_b = x_b;

  cvt_bf16_all<<<26880, 256, 0, stream>>>(x, x_b, qkv_w, qw_b, proj_w, pw_b);
  qkv_gemm<true><<<dim3(12, 256), 256, 0, stream>>>(x_b, qw_b, 0, q_b, k_b, vT_b);
  qkv_gemm<false><<<dim3(6, 256), 256, 0, stream>>>(x_b, qw_b, 1536, q_b, k_b, vT_b);
  attn_kernel<<<3072, 512, 0, stream>>>(q_b, k_b, vT_b, mask, bias_table, attn_b);
  proj_gemm<<<dim3(6, 256), 256, 0, stream>>>(attn_b, pw_b, proj_b, out);
}